// Round 5
// baseline (598.272 us; speedup 1.0000x reference)
//
#include <hip/hip_runtime.h>
#include <cstdint>
#include <cstddef>

// x: [512][64][1024], conv1: K=32 S=16 -> T=63, Cout=256
// z layout: [n][t][c] flat = (n*63+t)*256 + c
// fp16 2-limb: v ~= hi + lo*(1/2048), hi=fp16(v), lo=fp16((v-hi)*2048)

typedef _Float16 half8 __attribute__((ext_vector_type(8)));
typedef float floatx4 __attribute__((ext_vector_type(4)));

__device__ __forceinline__ void split_f32(float v, _Float16& hi, _Float16& lo) {
    _Float16 h = (_Float16)v;
    hi = h;
    lo = (_Float16)((v - (float)h) * 2048.0f);
}

// ---------------------------------------------------------------------------
// K0: prep — BN fold, fp16 limb splits of conv1_w, conv2_w(T), w1 (dense1)
// ---------------------------------------------------------------------------
__global__ __launch_bounds__(256) void prep_kernel(
    const float* __restrict__ c1w, const float* __restrict__ c1b,
    const float* __restrict__ g1,  const float* __restrict__ b1,
    const float* __restrict__ m1,  const float* __restrict__ v1,
    const float* __restrict__ c2w, const float* __restrict__ c2b,
    const float* __restrict__ g2,  const float* __restrict__ b2,
    const float* __restrict__ m2,  const float* __restrict__ v2,
    const float* __restrict__ w1,
    _Float16* __restrict__ w1h, _Float16* __restrict__ w1l,
    _Float16* __restrict__ w2h, _Float16* __restrict__ w2l,
    _Float16* __restrict__ wdh, _Float16* __restrict__ wdl,
    float* __restrict__ ab1, float* __restrict__ ab2)
{
    const int id = blockIdx.x * 256 + threadIdx.x;   // 65536 total
    if (id < 256) {
        float a1 = g1[id] / sqrtf(v1[id] + 1e-5f);
        ab1[id]       = a1;
        ab1[256 + id] = (c1b[id] - m1[id]) * a1 + b1[id];
        float a2 = g2[id] / sqrtf(v2[id] + 1e-5f);
        ab2[id]       = a2;
        ab2[256 + id] = (c2b[id] - m2[id]) * a2 + b2[id];
    }
    // dense1 weights: w1[o][c] row-major already == B-row layout [o][k=c]
    split_f32(w1[id], wdh[id], wdl[id]);
    // conv1_w limbs: [o][2048] direct layout
    for (int idx = id; idx < 256 * 2048; idx += 65536)
        split_f32(c1w[idx], w1h[idx], w1l[idx]);
    // conv2_w limbs transposed to [o][dt*256+c]
    for (int idx = id; idx < 256 * 768; idx += 65536) {
        const int o  = idx / 768;
        const int r  = idx - o * 768;
        const int dt = r >> 8;
        const int c  = r & 255;
        split_f32(c2w[o * 768 + c * 3 + dt], w2h[idx], w2l[idx]);
    }
}

// ---------------------------------------------------------------------------
// K1: conv1 + bn1, fp16 2-limb MFMA GEMM. M=32256, K=2048 (c*32+k), N=256.
// 128x128 tile, BK=64 (2 channels/iter), 4 waves (2x2), each 64x64 via
// 4x4 mfma_16x16x32_f16 x 2 k-groups. 96 MFMA per barrier pair.
// ---------------------------------------------------------------------------
__global__ __launch_bounds__(256, 2) void conv1_mfma(
    const float* __restrict__ x,
    const _Float16* __restrict__ w1h, const _Float16* __restrict__ w1l,
    const float* __restrict__ ab,
    _Float16* __restrict__ z1h, _Float16* __restrict__ z1l)
{
    __shared__ _Float16 Ah[8][128][8];   // [k-quad][m][8] fragment-major
    __shared__ _Float16 Al[8][128][8];
    __shared__ _Float16 Bh[8][128][8];
    __shared__ _Float16 Bl[8][128][8];

    const int tid = threadIdx.x;
    const int bm = blockIdx.x, bn = blockIdx.y;
    const int lr = tid & 127;          // staging row
    const int h  = tid >> 7;           // k-half 0..1

    const int am = bm * 128 + lr;
    const int an = am / 63, at = am - an * 63;
    const float*    arow  = x   + (size_t)an * 65536 + at * 16 + h * 16;
    const _Float16* bhrow = w1h + (size_t)(bn * 128 + lr) * 2048 + h * 32;
    const _Float16* blrow = w1l + (size_t)(bn * 128 + lr) * 2048 + h * 32;

    const int lane = tid & 63;
    const int wv   = tid >> 6;
    const int mw   = wv & 1, nw = wv >> 1;
    const int quad = lane >> 4;
    const int l15  = lane & 15;

    floatx4 accA[4][4] = {};
    floatx4 accB[4][4] = {};

    for (int it = 0; it < 32; ++it) {
        // channels c = 2it (window va) and 2it+1 (window vb); thread h covers
        // kk in [h*16, h*16+16) of each window.
        const float* ap0 = arow + (size_t)(2 * it)     * 1024;
        const float* ap1 = arow + (size_t)(2 * it + 1) * 1024;
        float va[16], vb[16];
        *(float4*)&va[0]  = *(const float4*)(ap0);
        *(float4*)&va[4]  = *(const float4*)(ap0 + 4);
        *(float4*)&va[8]  = *(const float4*)(ap0 + 8);
        *(float4*)&va[12] = *(const float4*)(ap0 + 12);
        *(float4*)&vb[0]  = *(const float4*)(ap1);
        *(float4*)&vb[4]  = *(const float4*)(ap1 + 4);
        *(float4*)&vb[8]  = *(const float4*)(ap1 + 8);
        *(float4*)&vb[12] = *(const float4*)(ap1 + 12);
        int4 bhv[4], blv[4];
#pragma unroll
        for (int q = 0; q < 4; ++q) {
            bhv[q] = *(const int4*)(bhrow + it * 64 + q * 8);
            blv[q] = *(const int4*)(blrow + it * 64 + q * 8);
        }

        union U { _Float16 hf[8]; int4 v; };
        U a0h, a0l, a1h, a1l, a2h, a2l, a3h, a3l;
#pragma unroll
        for (int j = 0; j < 8; ++j) split_f32(va[j],     a0h.hf[j], a0l.hf[j]);
#pragma unroll
        for (int j = 0; j < 8; ++j) split_f32(va[8 + j], a1h.hf[j], a1l.hf[j]);
#pragma unroll
        for (int j = 0; j < 8; ++j) split_f32(vb[j],     a2h.hf[j], a2l.hf[j]);
#pragma unroll
        for (int j = 0; j < 8; ++j) split_f32(vb[8 + j], a3h.hf[j], a3l.hf[j]);

        __syncthreads();               // prior iter's fragment reads done
        // A kquads: window0 -> h*2, h*2+1 ; window1 -> 4+h*2, 4+h*2+1
        *(int4*)&Ah[h*2    ][lr][0] = a0h.v;
        *(int4*)&Ah[h*2 + 1][lr][0] = a1h.v;
        *(int4*)&Ah[h*2 + 4][lr][0] = a2h.v;
        *(int4*)&Ah[h*2 + 5][lr][0] = a3h.v;
        *(int4*)&Al[h*2    ][lr][0] = a0l.v;
        *(int4*)&Al[h*2 + 1][lr][0] = a1l.v;
        *(int4*)&Al[h*2 + 4][lr][0] = a2l.v;
        *(int4*)&Al[h*2 + 5][lr][0] = a3l.v;
#pragma unroll
        for (int q = 0; q < 4; ++q) {
            *(int4*)&Bh[h*4 + q][lr][0] = bhv[q];
            *(int4*)&Bl[h*4 + q][lr][0] = blv[q];
        }
        __syncthreads();

#pragma unroll
        for (int g = 0; g < 2; ++g) {
            half8 fah[4], fal[4], fbh[4], fbl[4];
#pragma unroll
            for (int t = 0; t < 4; ++t) {
                fah[t] = *(const half8*)&Ah[g*4 + quad][mw*64 + t*16 + l15][0];
                fal[t] = *(const half8*)&Al[g*4 + quad][mw*64 + t*16 + l15][0];
                fbh[t] = *(const half8*)&Bh[g*4 + quad][nw*64 + t*16 + l15][0];
                fbl[t] = *(const half8*)&Bl[g*4 + quad][nw*64 + t*16 + l15][0];
            }
#pragma unroll
            for (int ti = 0; ti < 4; ++ti)
#pragma unroll
                for (int tj = 0; tj < 4; ++tj) {
                    accA[ti][tj] = __builtin_amdgcn_mfma_f32_16x16x32_f16(fah[ti], fbh[tj], accA[ti][tj], 0, 0, 0);
                    accB[ti][tj] = __builtin_amdgcn_mfma_f32_16x16x32_f16(fah[ti], fbl[tj], accB[ti][tj], 0, 0, 0);
                    accB[ti][tj] = __builtin_amdgcn_mfma_f32_16x16x32_f16(fal[ti], fbh[tj], accB[ti][tj], 0, 0, 0);
                }
        }
    }

    // epilogue: C/D layout col=lane&15 (n), row=quad*4+reg (m)
#pragma unroll
    for (int tj = 0; tj < 4; ++tj) {
        const int o = bn*128 + nw*64 + tj*16 + l15;
        const float alpha = ab[o], beta = ab[256 + o];
#pragma unroll
        for (int ti = 0; ti < 4; ++ti) {
            const int m0 = bm*128 + mw*64 + ti*16 + quad*4;
#pragma unroll
            for (int r = 0; r < 4; ++r) {
                float c = accA[ti][tj][r] + accB[ti][tj][r] * (1.0f/2048.0f);
                float z = c * alpha + beta;
                _Float16 zh, zl;
                split_f32(z, zh, zl);
                const size_t off = (size_t)(m0 + r) * 256 + o;
                z1h[off] = zh;
                z1l[off] = zl;
            }
        }
    }
}

// ---------------------------------------------------------------------------
// K2: conv2 + bn2, fp16 2-limb MFMA GEMM. K=768 (dt*256+c), BK=64,
// halo zero-fill. 96 MFMA per barrier pair.
// ---------------------------------------------------------------------------
__global__ __launch_bounds__(256, 2) void conv2_mfma(
    const _Float16* __restrict__ z1h, const _Float16* __restrict__ z1l,
    const _Float16* __restrict__ w2h, const _Float16* __restrict__ w2l,
    const float* __restrict__ ab, float* __restrict__ z2)
{
    __shared__ _Float16 Ah[8][128][8];
    __shared__ _Float16 Al[8][128][8];
    __shared__ _Float16 Bh[8][128][8];
    __shared__ _Float16 Bl[8][128][8];

    const int tid = threadIdx.x;
    const int bm = blockIdx.x, bn = blockIdx.y;
    const int lr = tid & 127;
    const int h  = tid >> 7;

    const int am = bm * 128 + lr;
    const int an = am / 63, at = am - an * 63;
    const _Float16* abase_h = z1h + (size_t)an * 16128;
    const _Float16* abase_l = z1l + (size_t)an * 16128;
    const _Float16* bhrow = w2h + (size_t)(bn * 128 + lr) * 768 + h * 32;
    const _Float16* blrow = w2l + (size_t)(bn * 128 + lr) * 768 + h * 32;

    const int lane = tid & 63;
    const int wv   = tid >> 6;
    const int mw   = wv & 1, nw = wv >> 1;
    const int quad = lane >> 4;
    const int l15  = lane & 15;

    floatx4 accA[4][4] = {};
    floatx4 accB[4][4] = {};

    const int4 z4 = {0, 0, 0, 0};

    for (int it = 0; it < 12; ++it) {
        const int k0 = it * 64;
        const int dt = k0 >> 8;        // 0..2 (no BK crossing: 256 % 64 == 0)
        const int c0 = (k0 & 255) + h * 32;
        const int trow = at + dt - 1;
        const bool valid = (trow >= 0) && (trow < 63);
        const _Float16* aph = abase_h + trow * 256 + c0;
        const _Float16* apl = abase_l + trow * 256 + c0;
        int4 ahv[4], alv[4], bhv[4], blv[4];
#pragma unroll
        for (int q = 0; q < 4; ++q) {
            ahv[q] = valid ? *(const int4*)(aph + q * 8) : z4;
            alv[q] = valid ? *(const int4*)(apl + q * 8) : z4;
            bhv[q] = *(const int4*)(bhrow + it * 64 + q * 8);
            blv[q] = *(const int4*)(blrow + it * 64 + q * 8);
        }

        __syncthreads();
#pragma unroll
        for (int q = 0; q < 4; ++q) {
            *(int4*)&Ah[h*4 + q][lr][0] = ahv[q];
            *(int4*)&Al[h*4 + q][lr][0] = alv[q];
            *(int4*)&Bh[h*4 + q][lr][0] = bhv[q];
            *(int4*)&Bl[h*4 + q][lr][0] = blv[q];
        }
        __syncthreads();

#pragma unroll
        for (int g = 0; g < 2; ++g) {
            half8 fah[4], fal[4], fbh[4], fbl[4];
#pragma unroll
            for (int t = 0; t < 4; ++t) {
                fah[t] = *(const half8*)&Ah[g*4 + quad][mw*64 + t*16 + l15][0];
                fal[t] = *(const half8*)&Al[g*4 + quad][mw*64 + t*16 + l15][0];
                fbh[t] = *(const half8*)&Bh[g*4 + quad][nw*64 + t*16 + l15][0];
                fbl[t] = *(const half8*)&Bl[g*4 + quad][nw*64 + t*16 + l15][0];
            }
#pragma unroll
            for (int ti = 0; ti < 4; ++ti)
#pragma unroll
                for (int tj = 0; tj < 4; ++tj) {
                    accA[ti][tj] = __builtin_amdgcn_mfma_f32_16x16x32_f16(fah[ti], fbh[tj], accA[ti][tj], 0, 0, 0);
                    accB[ti][tj] = __builtin_amdgcn_mfma_f32_16x16x32_f16(fah[ti], fbl[tj], accB[ti][tj], 0, 0, 0);
                    accB[ti][tj] = __builtin_amdgcn_mfma_f32_16x16x32_f16(fal[ti], fbh[tj], accB[ti][tj], 0, 0, 0);
                }
        }
    }

#pragma unroll
    for (int tj = 0; tj < 4; ++tj) {
        const int o = bn*128 + nw*64 + tj*16 + l15;
        const float alpha = ab[o], beta = ab[256 + o];
#pragma unroll
        for (int ti = 0; ti < 4; ++ti) {
            const int m0 = bm*128 + mw*64 + ti*16 + quad*4;
#pragma unroll
            for (int r = 0; r < 4; ++r) {
                float c = accA[ti][tj][r] + accB[ti][tj][r] * (1.0f/2048.0f);
                z2[(size_t)(m0 + r) * 256 + o] = c * alpha + beta;
            }
        }
    }
}

// ---------------------------------------------------------------------------
// K3a: cuba1 — z2 [n][t][c] -> binary spikes s1 (fp16 {0,1}) in [n][t][c].
// t-loop batched: 16 loads issued per chunk, recurrence runs from registers.
// ---------------------------------------------------------------------------
__global__ __launch_bounds__(256) void cuba1_kernel(
    const float* __restrict__ z2, _Float16* __restrict__ s1)
{
    const int n   = blockIdx.x;
    const int tid = threadIdx.x;
    const float* zrow = z2 + (size_t)n * 16128 + tid;
    _Float16*    srow = s1 + (size_t)n * 16128 + tid;
    float cur = 0.f, vol = 0.f;
    for (int tb = 0; tb < 4; ++tb) {
        const int base = tb * 16;
        const int nT   = (tb == 3) ? 15 : 16;
        float xv[16];
#pragma unroll
        for (int j = 0; j < 16; ++j)
            if (j < nT) xv[j] = zrow[(size_t)(base + j) * 256];
#pragma unroll
        for (int j = 0; j < 16; ++j) {
            if (j < nT) {
                cur = 0.1f * cur + xv[j];
                vol = 0.1f * vol + cur;
                bool sp = (vol - 0.3f) >= 0.f;
                srow[(size_t)(base + j) * 256] = sp ? (_Float16)1.0f : (_Float16)0.0f;
                if (sp) vol = 0.f;
            }
        }
    }
}

// ---------------------------------------------------------------------------
// K3b: dense1 via MFMA. y1[n*63+t][o] = sum_c s1[row][c] * w1[o][c].
// M=32256, K=256, N=256. A exact binary fp16 (1 limb), B 2-limb.
// ---------------------------------------------------------------------------
__global__ __launch_bounds__(256, 2) void dense1_mfma(
    const _Float16* __restrict__ s1,
    const _Float16* __restrict__ wdh, const _Float16* __restrict__ wdl,
    float* __restrict__ y1)
{
    __shared__ _Float16 As[4][128][8];
    __shared__ _Float16 Bh[4][128][8];
    __shared__ _Float16 Bl[4][128][8];

    const int tid = threadIdx.x;
    const int bm = blockIdx.x, bn = blockIdx.y;
    const int lr = tid & 127;
    const int h  = tid >> 7;

    const _Float16* arow  = s1  + (size_t)(bm * 128 + lr) * 256 + h * 16;
    const _Float16* bhrow = wdh + (size_t)(bn * 128 + lr) * 256 + h * 16;
    const _Float16* blrow = wdl + (size_t)(bn * 128 + lr) * 256 + h * 16;

    const int lane = tid & 63;
    const int wv   = tid >> 6;
    const int mw   = wv & 1, nw = wv >> 1;
    const int quad = lane >> 4;
    const int l15  = lane & 15;

    floatx4 accA[4][4] = {};
    floatx4 accB[4][4] = {};

    for (int it = 0; it < 8; ++it) {
        const int kap0 = it * 32;
        int4 a0 = *(const int4*)(arow + kap0);
        int4 a1 = *(const int4*)(arow + kap0 + 8);
        int4 b0h = *(const int4*)(bhrow + kap0);
        int4 b1h = *(const int4*)(bhrow + kap0 + 8);
        int4 b0l = *(const int4*)(blrow + kap0);
        int4 b1l = *(const int4*)(blrow + kap0 + 8);

        __syncthreads();
        *(int4*)&As[2*h  ][lr][0] = a0;
        *(int4*)&As[2*h+1][lr][0] = a1;
        *(int4*)&Bh[2*h  ][lr][0] = b0h;
        *(int4*)&Bh[2*h+1][lr][0] = b1h;
        *(int4*)&Bl[2*h  ][lr][0] = b0l;
        *(int4*)&Bl[2*h+1][lr][0] = b1l;
        __syncthreads();

        half8 fa[4], fbh[4], fbl[4];
#pragma unroll
        for (int t = 0; t < 4; ++t) {
            fa[t]  = *(const half8*)&As[quad][mw*64 + t*16 + l15][0];
            fbh[t] = *(const half8*)&Bh[quad][nw*64 + t*16 + l15][0];
            fbl[t] = *(const half8*)&Bl[quad][nw*64 + t*16 + l15][0];
        }
#pragma unroll
        for (int ti = 0; ti < 4; ++ti)
#pragma unroll
            for (int tj = 0; tj < 4; ++tj) {
                accA[ti][tj] = __builtin_amdgcn_mfma_f32_16x16x32_f16(fa[ti], fbh[tj], accA[ti][tj], 0, 0, 0);
                accB[ti][tj] = __builtin_amdgcn_mfma_f32_16x16x32_f16(fa[ti], fbl[tj], accB[ti][tj], 0, 0, 0);
            }
    }

#pragma unroll
    for (int tj = 0; tj < 4; ++tj) {
        const int o = bn*128 + nw*64 + tj*16 + l15;
#pragma unroll
        for (int ti = 0; ti < 4; ++ti) {
            const int m0 = bm*128 + mw*64 + ti*16 + quad*4;
#pragma unroll
            for (int r = 0; r < 4; ++r)
                y1[(size_t)(m0 + r) * 256 + o] =
                    accA[ti][tj][r] + accB[ti][tj][r] * (1.0f/2048.0f);
        }
    }
}

// ---------------------------------------------------------------------------
// K3c: cuba2 (per (n,o) over t, batched loads) -> masks -> dense2 -> cuba3
// ---------------------------------------------------------------------------
__global__ __launch_bounds__(256) void snn_tail(
    const float* __restrict__ y1, const float* __restrict__ w2,
    float* __restrict__ out)
{
    __shared__ unsigned long long M2[256];
    __shared__ float Y[2 * 63];
    const int n   = blockIdx.x;
    const int tid = threadIdx.x;

    // cuba2: thread = output channel o, reads y1[n][t][o] coalesced, batched
    {
        const float* yrow = y1 + (size_t)n * 16128 + tid;
        float v = 0.f;
        unsigned long long mask2 = 0ull;
        for (int tb = 0; tb < 4; ++tb) {
            const int base = tb * 16;
            const int nT   = (tb == 3) ? 15 : 16;
            float yv[16];
#pragma unroll
            for (int j = 0; j < 16; ++j)
                if (j < nT) yv[j] = yrow[(size_t)(base + j) * 256];
#pragma unroll
            for (int j = 0; j < 16; ++j) {
                if (j < nT) {
                    v = 0.9f * v + yv[j];          // cd=0 -> i = x
                    if ((v - 0.1f) >= 0.f) { mask2 |= (1ull << (base + j)); v = 0.f; }
                }
            }
        }
        M2[tid] = mask2;
    }
    __syncthreads();

    if (tid < 126) {
        const int cls = tid / 63;
        const int t   = tid - cls * 63;
        const float* wrow = w2 + cls * 256;
        float acc = 0.f;
#pragma unroll 4
        for (int o = 0; o < 256; ++o)
            acc += ((M2[o] >> t) & 1ull) ? wrow[o] : 0.f;
        Y[cls * 63 + t] = acc;
    }
    __syncthreads();
    if (tid < 2) {
        float v = 0.f;
        float* orow = out + (size_t)n * 126 + tid * 63;
        for (int t = 0; t < 63; ++t) {
            v = 0.9f * v + Y[tid * 63 + t];
            float u = v - 0.1f;
            float s = (u >= 0.f) ? 1.f : 0.f;
            orow[t] = s;
            v = (u >= 0.f) ? 0.f : v;
        }
    }
}

// ---------------------------------------------------------------------------
extern "C" void kernel_launch(void* const* d_in, const int* in_sizes, int n_in,
                              void* d_out, int out_size, void* d_ws, size_t ws_size,
                              hipStream_t stream)
{
    const float* x    = (const float*)d_in[0];
    const float* c1w  = (const float*)d_in[1];
    const float* c1b  = (const float*)d_in[2];
    const float* g1   = (const float*)d_in[3];
    const float* b1   = (const float*)d_in[4];
    const float* m1   = (const float*)d_in[5];
    const float* v1   = (const float*)d_in[6];
    const float* c2w  = (const float*)d_in[7];
    const float* c2b  = (const float*)d_in[8];
    const float* g2   = (const float*)d_in[9];
    const float* b2   = (const float*)d_in[10];
    const float* m2   = (const float*)d_in[11];
    const float* v2   = (const float*)d_in[12];
    const float* w1   = (const float*)d_in[13];
    const float* w2   = (const float*)d_in[14];
    float* out = (float*)d_out;

    float* ws = (float*)d_ws;
    // region A: z1 limbs during conv; reused as y1 (fp32) after conv2
    float*    zA  = ws;                               // 8,257,536 f
    _Float16* z1h = (_Float16*)zA;
    _Float16* z1l = (_Float16*)(zA + 4128768);
    float*    y1  = zA;
    float*    z2  = zA + 8257536;                     // 8,257,536 f
    _Float16* s1  = (_Float16*)(z2 + 8257536);        // 4,128,768 f
    float*    wsp = z2 + 8257536 + 4128768;
    _Float16* w1h = (_Float16*)wsp;                   // 262,144 f
    _Float16* w1l = (_Float16*)(wsp + 262144);        // 262,144 f
    _Float16* w2h = (_Float16*)(wsp + 2*262144);                    //  98,304 f
    _Float16* w2l = (_Float16*)(wsp + 2*262144 + 98304);            //  98,304 f
    _Float16* wdh = (_Float16*)(wsp + 2*262144 + 2*98304);          //  32,768 f
    _Float16* wdl = (_Float16*)(wsp + 2*262144 + 2*98304 + 32768);  //  32,768 f
    float*    ab1 = wsp + 2*262144 + 2*98304 + 2*32768;
    float*    ab2 = ab1 + 512;

    prep_kernel<<<256, 256, 0, stream>>>(c1w, c1b, g1, b1, m1, v1,
                                         c2w, c2b, g2, b2, m2, v2,
                                         w1, w1h, w1l, w2h, w2l, wdh, wdl,
                                         ab1, ab2);
    conv1_mfma<<<dim3(252, 2), 256, 0, stream>>>(x, w1h, w1l, ab1, z1h, z1l);
    conv2_mfma<<<dim3(252, 2), 256, 0, stream>>>(z1h, z1l, w2h, w2l, ab2, z2);
    cuba1_kernel<<<512, 256, 0, stream>>>(z2, s1);
    dense1_mfma<<<dim3(252, 2), 256, 0, stream>>>(s1, wdh, wdl, y1);
    snn_tail<<<512, 256, 0, stream>>>(y1, w2, out);
}